// Round 3
// baseline (1288.098 us; speedup 1.0000x reference)
//
#include <hip/hip_runtime.h>
#include <hip/hip_bf16.h>
#include <math.h>

#define THREADS 256

// ---------- helpers ----------
__device__ inline void fma4(float4& a, float s, const float4 w) {
  a.x = fmaf(s, w.x, a.x);
  a.y = fmaf(s, w.y, a.y);
  a.z = fmaf(s, w.z, a.z);
  a.w = fmaf(s, w.w, a.w);
}

__device__ inline void lrelu4(float4& v) {
  v.x = v.x > 0.f ? v.x : 0.01f * v.x;
  v.y = v.y > 0.f ? v.y : 0.01f * v.y;
  v.z = v.z > 0.f ? v.z : 0.01f * v.z;
  v.w = v.w > 0.f ? v.w : 0.01f * v.w;
}

__device__ inline float dot4(const float4 a, const float4 b) {
  return a.x * b.x + a.y * b.y + a.z * b.z + a.w * b.w;
}

// order-preserving float -> uint for atomicMax
__device__ inline unsigned int encf(float f) {
  unsigned int b = __float_as_uint(f);
  return (b & 0x80000000u) ? ~b : (b | 0x80000000u);
}
__device__ inline float decf(unsigned int u) {
  unsigned int b = (u & 0x80000000u) ? (u ^ 0x80000000u) : ~u;
  return __uint_as_float(b);
}

// static extract from float4[8] register array (call only from fully-unrolled loops)
__device__ inline float getq(const float4 a[8], int i) {
  const float4 v = a[i >> 2];
  switch (i & 3) {
    case 0: return v.x;
    case 1: return v.y;
    case 2: return v.z;
    default: return v.w;
  }
}

// ---------- K0: zero-init scratch + output ----------
__global__ void k_init(unsigned int* __restrict__ segmax, float* __restrict__ segsum,
                       float* __restrict__ egsum, float* __restrict__ out,
                       int nseg, int neg, int ntgt) {
  int i = blockIdx.x * blockDim.x + threadIdx.x;
  if (i < nseg) { segmax[i] = 0u; segsum[i] = 0.f; }
  if (i < neg) egsum[i] = 0.f;
  if (i < ntgt) out[i] = 0.f;
}

// ---------- K1a: fold weights: WF[m][k][d], m=0:AL 1:BL 2:AR 3:BR ----------
// AL = P @ Lw[0:32], BL = P @ Lw[32:64], AR = P @ Rw[0:32], BR = P @ Rw[32:64]
__global__ void k_fold(const float* __restrict__ pw, const float* __restrict__ lw,
                       const float* __restrict__ rw, float* __restrict__ wf) {
  int id = blockIdx.x * THREADS + threadIdx.x;  // [0, 4*128*32)
  int m = id >> 12;
  int rem = id & 4095;
  int k = rem >> 5;
  int d = rem & 31;
  const float* W = (m < 2) ? lw : rw;
  int off = (m & 1) ? 32 : 0;
  const float* prow = pw + k * 32;
  float s = 0.f;
#pragma unroll
  for (int i = 0; i < 32; ++i) s = fmaf(prow[i], W[(off + i) * 32 + d], s);
  wf[id] = s;
}

// ---------- K1b: per-query folded constants (launched once for left, once for right) ----------
// qout[b][d] = bias[d] + sum_i( qp_src[b][i]*W[(64+i)*32+d] + qp_rel*W[(96+i)*32+d]
//                             + qp_time*W[(128+i)*32+d] + pb[i]*(W[i*32+d]+W[(32+i)*32+d]) )
// where qp_* = raw @ proj_w + proj_b (full projection incl. bias).
__global__ void k_query(const float* __restrict__ qs_raw, const float* __restrict__ qr_raw,
                        const float* __restrict__ qt_raw, const float* __restrict__ pw,
                        const float* __restrict__ pb, const float* __restrict__ W,
                        const float* __restrict__ bias, float* __restrict__ qout, int B) {
  __shared__ float qp[3][64][32];
  int t = threadIdx.x;
  for (int idx = t; idx < 3 * B * 32; idx += THREADS) {
    int m = idx / (B * 32);
    int rem = idx % (B * 32);
    int b = rem >> 5;
    int i = rem & 31;
    const float* qraw = (m == 0 ? qs_raw : (m == 1 ? qr_raw : qt_raw)) + b * 128;
    float s = pb[i];
    for (int k = 0; k < 128; ++k) s = fmaf(qraw[k], pw[k * 32 + i], s);
    qp[m][b][i] = s;
  }
  __syncthreads();
  for (int idx = t; idx < B * 32; idx += THREADS) {
    int b = idx >> 5;
    int d = idx & 31;
    float s = bias[d];
    for (int i = 0; i < 32; ++i) {
      s = fmaf(qp[0][b][i], W[(64 + i) * 32 + d], s);
      s = fmaf(qp[1][b][i], W[(96 + i) * 32 + d], s);
      s = fmaf(qp[2][b][i], W[(128 + i) * 32 + d], s);
      s = fmaf(pb[i], W[i * 32 + d] + W[(32 + i) * 32 + d], s);
    }
    qout[idx] = s;
  }
}

// ---------- K2: main per-edge kernel (2 edges / thread) ----------
__global__ __launch_bounds__(THREADS, 2)
void k_edge(const float* __restrict__ vi, const float* __restrict__ vj,
            const float* __restrict__ rel, const float* __restrict__ na,
            const float* __restrict__ wf, const float* __restrict__ qL,
            const float* __restrict__ qR, const float* __restrict__ cw,
            const float* __restrict__ cb, const int* __restrict__ eg,
            const int* __restrict__ svi, float* __restrict__ att,
            unsigned int* __restrict__ segmax, int E) {
  // LDS: 4 folded matrices [128][32] as float4[128][8] each = exactly 64 KB
  __shared__ float4 sm[4 * 1024];
  float4* sAL = sm;
  float4* sAR = sm + 2048;
  {
    const float4* w4 = (const float4*)wf;
    for (int i = threadIdx.x; i < 4096; i += THREADS) sm[i] = w4[i];
  }
  __syncthreads();
  float4* sBL = sm + 1024;
  float4* sBR = sm + 3072;

  long p = (long)blockIdx.x * THREADS + threadIdx.x;
  long e0 = 2 * p;
  if (e0 >= E) return;  // safe: after the only __syncthreads
  long e1 = e0 + 1;
  bool h1 = e1 < E;
  long e1c = h1 ? e1 : e0;

  // accumulators initialized with folded query constants (biases included)
  float4 al0[8], al1[8], ar0[8], ar1[8];
  {
    int g0 = eg[e0], g1 = eg[e1c];
    const float4* qL4 = (const float4*)qL;
    const float4* qR4 = (const float4*)qR;
#pragma unroll
    for (int d = 0; d < 8; ++d) {
      al0[d] = qL4[g0 * 8 + d];
      al1[d] = qL4[g1 * 8 + d];
      ar0[d] = qR4[g0 * 8 + d];
      ar1[d] = qR4[g1 * 8 + d];
    }
  }

  // ---- pass 1: vi @ AL -> al ----
  {
    const float4* x0 = (const float4*)(vi + e0 * 128);
    const float4* x1 = (const float4*)(vi + e1c * 128);
#pragma unroll 4
    for (int kc = 0; kc < 32; ++kc) {
      float4 v0 = x0[kc], v1 = x1[kc];
      const float4* wk = sAL + kc * 32;
#pragma unroll
      for (int d = 0; d < 8; ++d) { float4 w = wk[d];      fma4(al0[d], v0.x, w); fma4(al1[d], v1.x, w); }
#pragma unroll
      for (int d = 0; d < 8; ++d) { float4 w = wk[8 + d];  fma4(al0[d], v0.y, w); fma4(al1[d], v1.y, w); }
#pragma unroll
      for (int d = 0; d < 8; ++d) { float4 w = wk[16 + d]; fma4(al0[d], v0.z, w); fma4(al1[d], v1.z, w); }
#pragma unroll
      for (int d = 0; d < 8; ++d) { float4 w = wk[24 + d]; fma4(al0[d], v0.w, w); fma4(al1[d], v1.w, w); }
    }
  }
  // ---- pass 2: vj @ AR -> ar ----
  {
    const float4* x0 = (const float4*)(vj + e0 * 128);
    const float4* x1 = (const float4*)(vj + e1c * 128);
#pragma unroll 4
    for (int kc = 0; kc < 32; ++kc) {
      float4 v0 = x0[kc], v1 = x1[kc];
      const float4* wk = sAR + kc * 32;
#pragma unroll
      for (int d = 0; d < 8; ++d) { float4 w = wk[d];      fma4(ar0[d], v0.x, w); fma4(ar1[d], v1.x, w); }
#pragma unroll
      for (int d = 0; d < 8; ++d) { float4 w = wk[8 + d];  fma4(ar0[d], v0.y, w); fma4(ar1[d], v1.y, w); }
#pragma unroll
      for (int d = 0; d < 8; ++d) { float4 w = wk[16 + d]; fma4(ar0[d], v0.z, w); fma4(ar1[d], v1.z, w); }
#pragma unroll
      for (int d = 0; d < 8; ++d) { float4 w = wk[24 + d]; fma4(ar0[d], v0.w, w); fma4(ar1[d], v1.w, w); }
    }
  }
  // ---- pass 3: rel @ BL -> al  AND  rel @ BR -> ar (single stream of rel) ----
  {
    const float4* x0 = (const float4*)(rel + e0 * 128);
    const float4* x1 = (const float4*)(rel + e1c * 128);
#pragma unroll 2
    for (int kc = 0; kc < 32; ++kc) {
      float4 v0 = x0[kc], v1 = x1[kc];
      const float4* wl = sBL + kc * 32;
      const float4* wr = sBR + kc * 32;
#pragma unroll
      for (int d = 0; d < 8; ++d) {
        float4 a = wl[d];      float4 b = wr[d];
        fma4(al0[d], v0.x, a); fma4(al1[d], v1.x, a);
        fma4(ar0[d], v0.x, b); fma4(ar1[d], v1.x, b);
      }
#pragma unroll
      for (int d = 0; d < 8; ++d) {
        float4 a = wl[8 + d];  float4 b = wr[8 + d];
        fma4(al0[d], v0.y, a); fma4(al1[d], v1.y, a);
        fma4(ar0[d], v0.y, b); fma4(ar1[d], v1.y, b);
      }
#pragma unroll
      for (int d = 0; d < 8; ++d) {
        float4 a = wl[16 + d]; float4 b = wr[16 + d];
        fma4(al0[d], v0.z, a); fma4(al1[d], v1.z, a);
        fma4(ar0[d], v0.z, b); fma4(ar1[d], v1.z, b);
      }
#pragma unroll
      for (int d = 0; d < 8; ++d) {
        float4 a = wl[24 + d]; float4 b = wr[24 + d];
        fma4(al0[d], v0.w, a); fma4(al1[d], v1.w, a);
        fma4(ar0[d], v0.w, b); fma4(ar1[d], v1.w, b);
      }
    }
  }

  // ---- epilogue ----
#pragma unroll
  for (int d = 0; d < 8; ++d) { lrelu4(al0[d]); lrelu4(al1[d]); lrelu4(ar0[d]); lrelu4(ar1[d]); }

  // transition = sum_d lh_d * (rh@C + cb)_d
  //            = sum_i rh_i * (sum_d lh_d * C[i,d]) + sum_d lh_d * cb_d
  // (reassociated: no ch[] array -> 64 fewer live VGPRs)
  const float4* C4 = (const float4*)cw;
  const float4* cb4 = (const float4*)cb;
  float s0 = 0.f, s1 = 0.f;
#pragma unroll
  for (int d = 0; d < 8; ++d) {
    float4 c = cb4[d];
    s0 += dot4(al0[d], c);
    s1 += dot4(al1[d], c);
  }
#pragma unroll
  for (int i = 0; i < 32; ++i) {
    float u0 = 0.f, u1 = 0.f;
#pragma unroll
    for (int d = 0; d < 8; ++d) {
      float4 c = C4[i * 8 + d];
      u0 += dot4(al0[d], c);
      u1 += dot4(al1[d], c);
    }
    s0 = fmaf(getq(ar0, i), u0, s0);
    s1 = fmaf(getq(ar1, i), u1, s1);
  }

  float a0v = s0 * na[e0];
  att[e0] = a0v;
  atomicMax(&segmax[svi[e0]], encf(a0v));
  if (h1) {
    float a1v = s1 * na[e1];
    att[e1] = a1v;
    atomicMax(&segmax[svi[e1]], encf(a1v));
  }
}

// ---------- K3: e = exp(att - segmax) IN PLACE, accumulate segment sums ----------
__global__ void k_exp(float* __restrict__ att, const unsigned int* __restrict__ segmax,
                      const int* __restrict__ svi, float* __restrict__ segsum, int E) {
  int e = blockIdx.x * THREADS + threadIdx.x;
  if (e >= E) return;
  int s = svi[e];
  float v = expf(att[e] - decf(segmax[s]));
  att[e] = v;
  atomicAdd(&segsum[s], v);
}

// ---------- K4: soft = e/segsum (in place), LDS-binned eg sums ----------
__global__ void k_norm(float* __restrict__ ev, const float* __restrict__ segsum,
                       const int* __restrict__ svi, const int* __restrict__ eg,
                       float* __restrict__ egsum, int E) {
  __shared__ float bins[64];
  int t = threadIdx.x;
  if (t < 64) bins[t] = 0.f;
  __syncthreads();
  for (long e = (long)blockIdx.x * THREADS + t; e < E; e += (long)gridDim.x * THREADS) {
    float s = ev[e] / segsum[svi[e]];
    ev[e] = s;
    atomicAdd(&bins[eg[e]], s);
  }
  __syncthreads();
  if (t < 64) atomicAdd(&egsum[t], bins[t]);
}

// ---------- K5: scatter into targets ----------
__global__ void k_out(const float* __restrict__ ev, const float* __restrict__ egsum,
                      const int* __restrict__ eg, const int* __restrict__ svj,
                      float* __restrict__ out, int E) {
  int e = blockIdx.x * THREADS + threadIdx.x;
  if (e >= E) return;
  atomicAdd(&out[svj[e]], ev[e] / egsum[eg[e]]);
}

// ---------- launcher ----------
extern "C" void kernel_launch(void* const* d_in, const int* in_sizes, int n_in,
                              void* d_out, int out_size, void* d_ws, size_t ws_size,
                              hipStream_t stream) {
  const float* na  = (const float*)d_in[0];
  const float* hvi = (const float*)d_in[1];
  const float* hvj = (const float*)d_in[2];
  const float* rel = (const float*)d_in[3];
  const float* qsr = (const float*)d_in[4];
  const float* qrr = (const float*)d_in[5];
  const float* qtr = (const float*)d_in[6];
  const float* pw  = (const float*)d_in[7];
  const float* pb  = (const float*)d_in[8];
  const float* lw  = (const float*)d_in[9];
  const float* lb  = (const float*)d_in[10];
  const float* rw  = (const float*)d_in[11];
  const float* rb  = (const float*)d_in[12];
  const float* cw  = (const float*)d_in[13];
  const float* cb  = (const float*)d_in[14];
  const int* eg  = (const int*)d_in[15];
  const int* svi = (const int*)d_in[16];
  const int* svj = (const int*)d_in[17];

  const int E = in_sizes[0];
  const int B = in_sizes[4] / 128;
  const int NSEG = 50000;          // num_seg (fixed by problem setup)
  const int NTGT = out_size;       // num_targets

  // workspace layout (floats) — ~2.5 MB total
  float* ws = (float*)d_ws;
  float* WF = ws;                          // 4*128*32 = 16384
  float* QL = WF + 16384;                  // 64*32
  float* QR = QL + 2048;                   // 64*32
  float* ATT = QR + 2048;                  // E (re-used in place: att -> e -> soft)
  unsigned int* SEGMAX = (unsigned int*)(ATT + E);  // NSEG
  float* SEGSUM = (float*)(SEGMAX + NSEG);          // NSEG
  float* EGSUM = SEGSUM + NSEG;                     // B
  float* OUT = (float*)d_out;

  int initN = NSEG > NTGT ? NSEG : NTGT;
  k_init<<<(initN + THREADS - 1) / THREADS, THREADS, 0, stream>>>(SEGMAX, SEGSUM, EGSUM, OUT,
                                                                  NSEG, B, NTGT);
  k_fold<<<(4 * 128 * 32) / THREADS, THREADS, 0, stream>>>(pw, lw, rw, WF);
  k_query<<<1, THREADS, 0, stream>>>(qsr, qrr, qtr, pw, pb, lw, lb, QL, B);
  k_query<<<1, THREADS, 0, stream>>>(qsr, qrr, qtr, pw, pb, rw, rb, QR, B);

  int pairs = (E + 1) / 2;
  k_edge<<<(pairs + THREADS - 1) / THREADS, THREADS, 0, stream>>>(
      hvi, hvj, rel, na, WF, QL, QR, cw, cb, eg, svi, ATT, SEGMAX, E);

  int eblocks = (E + THREADS - 1) / THREADS;
  k_exp<<<eblocks, THREADS, 0, stream>>>(ATT, SEGMAX, svi, SEGSUM, E);
  k_norm<<<512, THREADS, 0, stream>>>(ATT, SEGSUM, svi, eg, EGSUM, E);
  k_out<<<eblocks, THREADS, 0, stream>>>(ATT, EGSUM, eg, svj, OUT, E);
}

// Round 4
// 1018.404 us; speedup vs baseline: 1.2648x; 1.2648x over previous
//
#include <hip/hip_runtime.h>
#include <hip/hip_bf16.h>
#include <math.h>

#define THREADS 256

// order-preserving float -> uint for atomicMax
__device__ inline unsigned int encf(float f) {
  unsigned int b = __float_as_uint(f);
  return (b & 0x80000000u) ? ~b : (b | 0x80000000u);
}
__device__ inline float decf(unsigned int u) {
  unsigned int b = (u & 0x80000000u) ? (u ^ 0x80000000u) : ~u;
  return __uint_as_float(b);
}

// ---------- K0: zero-init scratch + output ----------
__global__ void k_init(unsigned int* __restrict__ segmax, float* __restrict__ segsum,
                       float* __restrict__ egsum, float* __restrict__ out,
                       int nseg, int neg, int ntgt) {
  int i = blockIdx.x * blockDim.x + threadIdx.x;
  if (i < nseg) { segmax[i] = 0u; segsum[i] = 0.f; }
  if (i < neg) egsum[i] = 0.f;
  if (i < ntgt) out[i] = 0.f;
}

// ---------- K1a: fold weights: WF[m][k][d], m=0:AL 1:BL 2:AR 3:BR ----------
__global__ void k_fold(const float* __restrict__ pw, const float* __restrict__ lw,
                       const float* __restrict__ rw, float* __restrict__ wf) {
  int id = blockIdx.x * THREADS + threadIdx.x;  // [0, 4*128*32)
  int m = id >> 12;
  int rem = id & 4095;
  int k = rem >> 5;
  int d = rem & 31;
  const float* W = (m < 2) ? lw : rw;
  int off = (m & 1) ? 32 : 0;
  const float* prow = pw + k * 32;
  float s = 0.f;
#pragma unroll
  for (int i = 0; i < 32; ++i) s = fmaf(prow[i], W[(off + i) * 32 + d], s);
  wf[id] = s;
}

// ---------- K1b-1: qp[m][b][i] = (q_raw[m][b] @ proj_w + proj_b)[i]  (grid-parallel) ----------
__global__ void k_qproj(const float* __restrict__ qs, const float* __restrict__ qr,
                        const float* __restrict__ qt, const float* __restrict__ pw,
                        const float* __restrict__ pb, float* __restrict__ qp, int B) {
  int idx = blockIdx.x * THREADS + threadIdx.x;  // [0, 3*B*32)
  if (idx >= 3 * B * 32) return;
  int m = idx / (B * 32);
  int rem = idx % (B * 32);
  int b = rem >> 5;
  int i = rem & 31;
  const float* qraw = (m == 0 ? qs : (m == 1 ? qr : qt)) + b * 128;
  float a0 = 0.f, a1 = 0.f, a2 = 0.f, a3 = 0.f;
#pragma unroll
  for (int k = 0; k < 128; k += 4) {
    a0 = fmaf(qraw[k],     pw[k * 32 + i],       a0);
    a1 = fmaf(qraw[k + 1], pw[(k + 1) * 32 + i], a1);
    a2 = fmaf(qraw[k + 2], pw[(k + 2) * 32 + i], a2);
    a3 = fmaf(qraw[k + 3], pw[(k + 3) * 32 + i], a3);
  }
  qp[idx] = pb[i] + ((a0 + a1) + (a2 + a3));
}

// ---------- K1b-2: fold per-query constants for BOTH sides ----------
// q{L,R}[b][d] = bias[d] + sum_i( qp0*W[64+i] + qp1*W[96+i] + qp2*W[128+i]
//                                + pb[i]*(W[i]+W[32+i]) )[col d]
__global__ void k_qfold(const float* __restrict__ qp, const float* __restrict__ pb,
                        const float* __restrict__ lw, const float* __restrict__ lb,
                        const float* __restrict__ rw, const float* __restrict__ rb,
                        float* __restrict__ qL, float* __restrict__ qR, int B) {
  int idx = blockIdx.x * THREADS + threadIdx.x;  // [0, 2*B*32)
  if (idx >= 2 * B * 32) return;
  int side = idx / (B * 32);
  int rem = idx % (B * 32);
  int b = rem >> 5;
  int d = rem & 31;
  const float* W = side ? rw : lw;
  const float* bias = side ? rb : lb;
  float s = bias[d];
#pragma unroll 4
  for (int i = 0; i < 32; ++i) {
    s = fmaf(qp[0 * B * 32 + b * 32 + i], W[(64 + i) * 32 + d], s);
    s = fmaf(qp[1 * B * 32 + b * 32 + i], W[(96 + i) * 32 + d], s);
    s = fmaf(qp[2 * B * 32 + b * 32 + i], W[(128 + i) * 32 + d], s);
    s = fmaf(pb[i], W[i * 32 + d] + W[(32 + i) * 32 + d], s);
  }
  (side ? qR : qL)[b * 32 + d] = s;
}

// ---------- K2: main per-edge kernel (2 edges / thread, SGPR weights, no LDS) ----------
// Weights are wave-uniform: read at loop-uniform addresses with constant offsets so
// the compiler emits s_load -> SGPR, and v_fma takes the weight as a scalar operand.
// This removes the 1024 B/instr LDS->RF broadcast cost that capped VALUBusy at ~50%.
__global__ __launch_bounds__(THREADS, 2)
void k_edge(const float* __restrict__ vi, const float* __restrict__ vj,
            const float* __restrict__ rel, const float* __restrict__ na,
            const float* __restrict__ wf, const float* __restrict__ qL,
            const float* __restrict__ qR, const float* __restrict__ cw,
            const float* __restrict__ cb, const int* __restrict__ eg,
            const int* __restrict__ svi, float* __restrict__ att,
            unsigned int* __restrict__ segmax, int E) {
  long p = (long)blockIdx.x * THREADS + threadIdx.x;
  long e0 = 2 * p;
  long e1 = e0 + 1;
  // clamp instead of early-return: keeps control flow wave-uniform for the
  // scalarizer; only the final stores are guarded.
  long e0c = e0 < E ? e0 : (long)(E - 1);
  long e1c = e1 < E ? e1 : (long)(E - 1);

  float al0[32], al1[32], ar0[32], ar1[32];
  {
    int g0 = eg[e0c], g1 = eg[e1c];
    const float4* qL4 = (const float4*)qL;
    const float4* qR4 = (const float4*)qR;
#pragma unroll
    for (int d4 = 0; d4 < 8; ++d4) {
      float4 a = qL4[g0 * 8 + d4];
      al0[4 * d4] = a.x; al0[4 * d4 + 1] = a.y; al0[4 * d4 + 2] = a.z; al0[4 * d4 + 3] = a.w;
      float4 b = qL4[g1 * 8 + d4];
      al1[4 * d4] = b.x; al1[4 * d4 + 1] = b.y; al1[4 * d4 + 2] = b.z; al1[4 * d4 + 3] = b.w;
      float4 c = qR4[g0 * 8 + d4];
      ar0[4 * d4] = c.x; ar0[4 * d4 + 1] = c.y; ar0[4 * d4 + 2] = c.z; ar0[4 * d4 + 3] = c.w;
      float4 e = qR4[g1 * 8 + d4];
      ar1[4 * d4] = e.x; ar1[4 * d4 + 1] = e.y; ar1[4 * d4 + 2] = e.z; ar1[4 * d4 + 3] = e.w;
    }
  }

  // ---- pass 1: vi @ AL -> al ----
  {
    const float4* x0 = (const float4*)(vi + e0c * 128);
    const float4* x1 = (const float4*)(vi + e1c * 128);
    const float* W = wf;  // AL
#pragma unroll 2
    for (int kc = 0; kc < 32; ++kc) {
      float4 v0 = x0[kc], v1 = x1[kc];
      const float* wk = W + kc * 128;
#pragma unroll
      for (int d = 0; d < 32; ++d) { float w = wk[d];      al0[d] = fmaf(v0.x, w, al0[d]); al1[d] = fmaf(v1.x, w, al1[d]); }
#pragma unroll
      for (int d = 0; d < 32; ++d) { float w = wk[32 + d]; al0[d] = fmaf(v0.y, w, al0[d]); al1[d] = fmaf(v1.y, w, al1[d]); }
#pragma unroll
      for (int d = 0; d < 32; ++d) { float w = wk[64 + d]; al0[d] = fmaf(v0.z, w, al0[d]); al1[d] = fmaf(v1.z, w, al1[d]); }
#pragma unroll
      for (int d = 0; d < 32; ++d) { float w = wk[96 + d]; al0[d] = fmaf(v0.w, w, al0[d]); al1[d] = fmaf(v1.w, w, al1[d]); }
    }
  }
  // ---- pass 2: vj @ AR -> ar ----
  {
    const float4* x0 = (const float4*)(vj + e0c * 128);
    const float4* x1 = (const float4*)(vj + e1c * 128);
    const float* W = wf + 2 * 4096;  // AR
#pragma unroll 2
    for (int kc = 0; kc < 32; ++kc) {
      float4 v0 = x0[kc], v1 = x1[kc];
      const float* wk = W + kc * 128;
#pragma unroll
      for (int d = 0; d < 32; ++d) { float w = wk[d];      ar0[d] = fmaf(v0.x, w, ar0[d]); ar1[d] = fmaf(v1.x, w, ar1[d]); }
#pragma unroll
      for (int d = 0; d < 32; ++d) { float w = wk[32 + d]; ar0[d] = fmaf(v0.y, w, ar0[d]); ar1[d] = fmaf(v1.y, w, ar1[d]); }
#pragma unroll
      for (int d = 0; d < 32; ++d) { float w = wk[64 + d]; ar0[d] = fmaf(v0.z, w, ar0[d]); ar1[d] = fmaf(v1.z, w, ar1[d]); }
#pragma unroll
      for (int d = 0; d < 32; ++d) { float w = wk[96 + d]; ar0[d] = fmaf(v0.w, w, ar0[d]); ar1[d] = fmaf(v1.w, w, ar1[d]); }
    }
  }
  // ---- pass 3: rel @ BL -> al AND rel @ BR -> ar (single stream of rel) ----
  {
    const float4* x0 = (const float4*)(rel + e0c * 128);
    const float4* x1 = (const float4*)(rel + e1c * 128);
    const float* WL = wf + 4096;      // BL
    const float* WR = wf + 3 * 4096;  // BR
    for (int kc = 0; kc < 32; ++kc) {
      float4 v0 = x0[kc], v1 = x1[kc];
      const float* wl = WL + kc * 128;
      const float* wr = WR + kc * 128;
#pragma unroll
      for (int d = 0; d < 32; ++d) {
        float a = wl[d];      float b = wr[d];
        al0[d] = fmaf(v0.x, a, al0[d]); al1[d] = fmaf(v1.x, a, al1[d]);
        ar0[d] = fmaf(v0.x, b, ar0[d]); ar1[d] = fmaf(v1.x, b, ar1[d]);
      }
#pragma unroll
      for (int d = 0; d < 32; ++d) {
        float a = wl[32 + d]; float b = wr[32 + d];
        al0[d] = fmaf(v0.y, a, al0[d]); al1[d] = fmaf(v1.y, a, al1[d]);
        ar0[d] = fmaf(v0.y, b, ar0[d]); ar1[d] = fmaf(v1.y, b, ar1[d]);
      }
#pragma unroll
      for (int d = 0; d < 32; ++d) {
        float a = wl[64 + d]; float b = wr[64 + d];
        al0[d] = fmaf(v0.z, a, al0[d]); al1[d] = fmaf(v1.z, a, al1[d]);
        ar0[d] = fmaf(v0.z, b, ar0[d]); ar1[d] = fmaf(v1.z, b, ar1[d]);
      }
#pragma unroll
      for (int d = 0; d < 32; ++d) {
        float a = wl[96 + d]; float b = wr[96 + d];
        al0[d] = fmaf(v0.w, a, al0[d]); al1[d] = fmaf(v1.w, a, al1[d]);
        ar0[d] = fmaf(v0.w, b, ar0[d]); ar1[d] = fmaf(v1.w, b, ar1[d]);
      }
    }
  }

  // ---- epilogue: leaky-relu; transition = sum_i rh_i*(sum_d lh_d*C[i,d]) + lh.cb ----
#pragma unroll
  for (int d = 0; d < 32; ++d) {
    al0[d] = al0[d] > 0.f ? al0[d] : 0.01f * al0[d];
    al1[d] = al1[d] > 0.f ? al1[d] : 0.01f * al1[d];
    ar0[d] = ar0[d] > 0.f ? ar0[d] : 0.01f * ar0[d];
    ar1[d] = ar1[d] > 0.f ? ar1[d] : 0.01f * ar1[d];
  }
  float s0 = 0.f, s1 = 0.f;
#pragma unroll
  for (int d = 0; d < 32; ++d) { float c = cb[d]; s0 = fmaf(al0[d], c, s0); s1 = fmaf(al1[d], c, s1); }
#pragma unroll
  for (int i = 0; i < 32; ++i) {
    float u0 = 0.f, u1 = 0.f;
#pragma unroll
    for (int d = 0; d < 32; ++d) {
      float c = cw[i * 32 + d];
      u0 = fmaf(al0[d], c, u0);
      u1 = fmaf(al1[d], c, u1);
    }
    s0 = fmaf(ar0[i], u0, s0);
    s1 = fmaf(ar1[i], u1, s1);
  }

  if (e0 < E) {
    float a0v = s0 * na[e0];
    att[e0] = a0v;
    atomicMax(&segmax[svi[e0]], encf(a0v));
  }
  if (e1 < E) {
    float a1v = s1 * na[e1];
    att[e1] = a1v;
    atomicMax(&segmax[svi[e1]], encf(a1v));
  }
}

// ---------- K3: e = exp(att - segmax) IN PLACE, accumulate segment sums ----------
__global__ void k_exp(float* __restrict__ att, const unsigned int* __restrict__ segmax,
                      const int* __restrict__ svi, float* __restrict__ segsum, int E) {
  int e = blockIdx.x * THREADS + threadIdx.x;
  if (e >= E) return;
  int s = svi[e];
  float v = expf(att[e] - decf(segmax[s]));
  att[e] = v;
  atomicAdd(&segsum[s], v);
}

// ---------- K4: soft = e/segsum (in place), LDS-binned eg sums ----------
__global__ void k_norm(float* __restrict__ ev, const float* __restrict__ segsum,
                       const int* __restrict__ svi, const int* __restrict__ eg,
                       float* __restrict__ egsum, int E) {
  __shared__ float bins[64];
  int t = threadIdx.x;
  if (t < 64) bins[t] = 0.f;
  __syncthreads();
  for (long e = (long)blockIdx.x * THREADS + t; e < E; e += (long)gridDim.x * THREADS) {
    float s = ev[e] / segsum[svi[e]];
    ev[e] = s;
    atomicAdd(&bins[eg[e]], s);
  }
  __syncthreads();
  if (t < 64) atomicAdd(&egsum[t], bins[t]);
}

// ---------- K5: scatter into targets ----------
__global__ void k_out(const float* __restrict__ ev, const float* __restrict__ egsum,
                      const int* __restrict__ eg, const int* __restrict__ svj,
                      float* __restrict__ out, int E) {
  int e = blockIdx.x * THREADS + threadIdx.x;
  if (e >= E) return;
  atomicAdd(&out[svj[e]], ev[e] / egsum[eg[e]]);
}

// ---------- launcher ----------
extern "C" void kernel_launch(void* const* d_in, const int* in_sizes, int n_in,
                              void* d_out, int out_size, void* d_ws, size_t ws_size,
                              hipStream_t stream) {
  const float* na  = (const float*)d_in[0];
  const float* hvi = (const float*)d_in[1];
  const float* hvj = (const float*)d_in[2];
  const float* rel = (const float*)d_in[3];
  const float* qsr = (const float*)d_in[4];
  const float* qrr = (const float*)d_in[5];
  const float* qtr = (const float*)d_in[6];
  const float* pw  = (const float*)d_in[7];
  const float* pb  = (const float*)d_in[8];
  const float* lw  = (const float*)d_in[9];
  const float* lb  = (const float*)d_in[10];
  const float* rw  = (const float*)d_in[11];
  const float* rb  = (const float*)d_in[12];
  const float* cw  = (const float*)d_in[13];
  const float* cb  = (const float*)d_in[14];
  const int* eg  = (const int*)d_in[15];
  const int* svi = (const int*)d_in[16];
  const int* svj = (const int*)d_in[17];

  const int E = in_sizes[0];
  const int B = in_sizes[4] / 128;
  const int NSEG = 50000;          // num_seg (fixed by problem setup)
  const int NTGT = out_size;       // num_targets

  // workspace layout (floats) — ~2.5 MB total
  float* ws = (float*)d_ws;
  float* WF = ws;                                   // 4*128*32 = 16384
  float* QL = WF + 16384;                           // B*32
  float* QR = QL + 2048;                            // B*32
  float* QP = QR + 2048;                            // 3*B*32
  float* ATT = QP + 6144;                           // E (in place: att -> e -> soft)
  unsigned int* SEGMAX = (unsigned int*)(ATT + E);  // NSEG
  float* SEGSUM = (float*)(SEGMAX + NSEG);          // NSEG
  float* EGSUM = SEGSUM + NSEG;                     // B
  float* OUT = (float*)d_out;

  int initN = NSEG > NTGT ? NSEG : NTGT;
  k_init<<<(initN + THREADS - 1) / THREADS, THREADS, 0, stream>>>(SEGMAX, SEGSUM, EGSUM, OUT,
                                                                  NSEG, B, NTGT);
  k_fold<<<(4 * 128 * 32) / THREADS, THREADS, 0, stream>>>(pw, lw, rw, WF);
  k_qproj<<<(3 * B * 32 + THREADS - 1) / THREADS, THREADS, 0, stream>>>(qsr, qrr, qtr, pw, pb, QP, B);
  k_qfold<<<(2 * B * 32 + THREADS - 1) / THREADS, THREADS, 0, stream>>>(QP, pb, lw, lb, rw, rb, QL, QR, B);

  int pairs = (E + 1) / 2;
  k_edge<<<(pairs + THREADS - 1) / THREADS, THREADS, 0, stream>>>(
      hvi, hvj, rel, na, WF, QL, QR, cw, cb, eg, svi, ATT, SEGMAX, E);

  int eblocks = (E + THREADS - 1) / THREADS;
  k_exp<<<eblocks, THREADS, 0, stream>>>(ATT, SEGMAX, svi, SEGSUM, E);
  k_norm<<<512, THREADS, 0, stream>>>(ATT, SEGSUM, svi, eg, EGSUM, E);
  k_out<<<eblocks, THREADS, 0, stream>>>(ATT, EGSUM, eg, svj, OUT, E);
}